// Round 14
// baseline (1371.539 us; speedup 1.0000x reference)
//
#include <hip/hip_runtime.h>
#include <math.h>
#include <float.h>

#define BN_EPS 1e-5f

// Exact (non-contracted) squared distance, matching numpy's mul-then-add
// left-to-right association. Critical: FPS/KNN *selections* must match ref.
__device__ __forceinline__ float sqdist_exact(float dx, float dy, float dz) {
  return __fadd_rn(__fadd_rn(__fmul_rn(dx, dx), __fmul_rn(dy, dy)), __fmul_rn(dz, dz));
}

// ---------------- FPS v6: u64-key DPP reduce (proven best) ----------------
// Key = (float_bits(dist) << 32) | ~index  (dist>=0 => IEEE order == uint
// order; max key == max dist, first-index tie-break, matches jnp.argmax).
// Session lessons (rounds 2-9): <16,4> (1 wave/SIMD) is optimal for fps1;
// coord-carry through the DPP chain spills (v7/v8/v10); issue-count reduction
// is useless (v5/v11: latency-chain-bound). ~600 µs is fps1's floor.
#define DPP_STEP(CTRL)                                                                   \
  {                                                                                      \
    unsigned int nhi = (unsigned int)__builtin_amdgcn_update_dpp((int)khi, (int)khi,     \
                                                                 CTRL, 0xf, 0xf, false); \
    unsigned int nlo = (unsigned int)__builtin_amdgcn_update_dpp((int)klo, (int)klo,     \
                                                                 CTRL, 0xf, 0xf, false); \
    unsigned long long nk = (((unsigned long long)nhi) << 32) | nlo;                     \
    if (nk > wk) { wk = nk; khi = nhi; klo = nlo; }                                      \
  }

// fps body shared by fused kernels. Caller guarantees:
// - threads t in [0, NW*64) call this (NW==1 body has NO barriers);
// - for NW>1 all blockDim threads enter (barriers are block-local).
template <int P, int NW>
__device__ __forceinline__ void fps_body(const float* __restrict__ pb,
                                         float* __restrict__ newp_b,
                                         float* spts, float* snew,
                                         unsigned long long* slots, int t) {
  constexpr int BS = NW * 64;
  constexpr int N = P * BS;
  constexpr int M = N / 4;
  const int wv = t >> 6;
  const int lane = t & 63;
  float px[P], py[P], pz[P], md[P];
#pragma unroll
  for (int j = 0; j < P; j++) {
    int i = j * BS + t;
    float x = pb[3 * i], y = pb[3 * i + 1], z = pb[3 * i + 2];
    px[j] = x; py[j] = y; pz[j] = z; md[j] = INFINITY;
    spts[3 * i] = x; spts[3 * i + 1] = y; spts[3 * i + 2] = z;
  }
  float lx = pb[0], ly = pb[1], lz = pb[2];
  if (t == 0) {
    if constexpr (NW > 1) {
      snew[0] = lx; snew[1] = ly; snew[2] = lz;
    } else {
      newp_b[0] = lx; newp_b[1] = ly; newp_b[2] = lz;
    }
  }

  for (int r = 1; r < M; r++) {
    float bv; int bi;
    {
      float d0 = sqdist_exact(px[0] - lx, py[0] - ly, pz[0] - lz);
      float m0 = fminf(md[0], d0);
      md[0] = m0;
      bv = m0; bi = t;
    }
#pragma unroll
    for (int j = 1; j < P; j++) {
      float d = sqdist_exact(px[j] - lx, py[j] - ly, pz[j] - lz);
      float m = fminf(md[j], d);
      md[j] = m;
      if (m > bv) { bv = m; bi = j * BS + t; }  // strict >: first-index ties
    }
    unsigned int khi = __float_as_uint(bv);
    unsigned int klo = ~(unsigned int)bi;
    unsigned long long wk = (((unsigned long long)khi) << 32) | klo;
    DPP_STEP(0x111);  // row_shr:1
    DPP_STEP(0x112);  // row_shr:2
    DPP_STEP(0x114);  // row_shr:4
    DPP_STEP(0x118);  // row_shr:8
    DPP_STEP(0x142);  // row_bcast:15
    DPP_STEP(0x143);  // row_bcast:31
    unsigned int gidx;
    if constexpr (NW == 1) {
      unsigned int wlo = (unsigned int)__builtin_amdgcn_readlane((int)wk, 63);
      gidx = ~wlo;
    } else {
      unsigned long long* base = slots + (r & 1) * NW;
      if (lane == 63) base[wv] = wk;
      __syncthreads();
      unsigned long long fk = base[0];
#pragma unroll
      for (int w = 1; w < NW; w++) {
        unsigned long long k2 = base[w];
        if (k2 > fk) fk = k2;
      }
      gidx = ~(unsigned int)fk;
    }
    lx = spts[3 * gidx];
    ly = spts[3 * gidx + 1];
    lz = spts[3 * gidx + 2];
    if (t == 0) {
      if constexpr (NW > 1) {
        snew[3 * r] = lx; snew[3 * r + 1] = ly; snew[3 * r + 2] = lz;
      } else {
        newp_b[3 * r] = lx; newp_b[3 * r + 1] = ly; newp_b[3 * r + 2] = lz;
      }
    }
  }
  if constexpr (NW > 1) {
    __syncthreads();
    for (int i = t; i < M * 3; i += BS) newp_b[i] = snew[i];
  }
}

// knn body (no barriers).
__device__ __forceinline__ void knn_body(const float* __restrict__ p,
                                         const float* __restrict__ newp,
                                         int N, int M, int BM,
                                         int* __restrict__ nidx,
                                         int gwid, int lane) {
  if (gwid >= BM) return;
  int b = gwid / M;
  const float* pb = p + (size_t)b * N * 3;
  float qx = newp[(size_t)gwid * 3], qy = newp[(size_t)gwid * 3 + 1], qz = newp[(size_t)gwid * 3 + 2];
  float bd[16];
  int bi[16];
#pragma unroll
  for (int s = 0; s < 16; s++) { bd[s] = INFINITY; bi[s] = 0x7FFFFFFF; }
  for (int c = lane; c < N; c += 64) {
    float d = sqdist_exact(pb[3 * c] - qx, pb[3 * c + 1] - qy, pb[3 * c + 2] - qz);
    if (d < bd[15]) {
      bd[15] = d; bi[15] = c;
#pragma unroll
      for (int s = 15; s >= 1; --s) {
        bool sw = bd[s] < bd[s - 1];
        if (sw) {
          float tf = bd[s]; bd[s] = bd[s - 1]; bd[s - 1] = tf;
          int ti = bi[s]; bi[s] = bi[s - 1]; bi[s - 1] = ti;
        }
      }
    }
  }
  int out = 0;
  for (int r = 0; r < 16; r++) {
    float v = bd[0]; int ii = bi[0];
    float mv = v; int mi = ii;
#pragma unroll
    for (int m = 1; m < 64; m <<= 1) {
      float v2 = __shfl_xor(mv, m);
      int i2 = __shfl_xor(mi, m);
      if (v2 < mv || (v2 == mv && i2 < mi)) { mv = v2; mi = i2; }
    }
    if (mi == ii) {
#pragma unroll
      for (int s = 0; s < 15; s++) { bd[s] = bd[s + 1]; bi[s] = bi[s + 1]; }
      bd[15] = INFINITY; bi[15] = 0x7FFFFFFF;
    }
    if (lane == r) out = mi;
  }
  if (lane < 16) nidx[(size_t)gwid * 16 + lane] = out;
}

// stats body: per-channel sum/sumsq. Same tid/stride mapping as the original
// standalone stats_kernel (nb=256 virtual blocks) -> bit-identical per-thread
// partial sums; only atomic order differs (tolerated jitter).
__device__ __forceinline__ void stats_body(const float* __restrict__ v, int n, int D,
                                           float* __restrict__ partial, float* sm,
                                           int bid, int nb, int t) {
  int tid = bid * 256 + t;
  int stride = 256 * nb;
  float s = 0.f, q = 0.f;
  for (int i = tid; i < n; i += stride) { float a = v[i]; s += a; q += a * a; }
  int c = tid % D;
  for (int i = t; i < 2 * D; i += 256) sm[i] = 0.f;
  __syncthreads();
  atomicAdd(&sm[c], s);
  atomicAdd(&sm[D + c], q);
  __syncthreads();
  for (int i = t; i < 2 * D; i += 256)
    atomicAdd(&partial[(bid & 63) * 2 * D + i], sm[i]);
}

// gemm body with INLINE input-BN: computes scale/shift from the input stage's
// PART stats (same 64-slot j-order reduction as the old finalize/bn kernels ->
// bit-identical sc/sh), then applies fmax(raw*sc+sh, 0) per gathered element
// with a per-channel POINTER SELECT (sc>=0 ? ymax : ymin) -> single load.
__device__ __forceinline__ void gemm_body(
    float* sm, const float* __restrict__ p, const float* __restrict__ h,
    const float* __restrict__ hmin, const float* __restrict__ newp,
    const int* __restrict__ nidx, const float* __restrict__ W,
    const float* __restrict__ bnp, const float* __restrict__ bng,
    const float* __restrict__ bnb, float bncnt,
    float* __restrict__ ymax, float* __restrict__ ymin,
    float* __restrict__ partial, int N, int M, int BM, int Ch, int Cpad, int D,
    int Gseq, int bid, int t) {
  int Ctot = Ch + 3;
  int TD = D < 256 ? D : 256;
  int Gpar = 256 / TD;
  float* sfeat = sm;                      // Gpar*16*Cpad
  float* sstat = sm + Gpar * 16 * Cpad;   // 2*D
  float* sbn   = sstat + 2 * D;           // 2*Ch
  for (int i = t; i < 2 * D; i += 256) sstat[i] = 0.f;
  for (int d = t; d < Ch; d += 256) {
    float s = 0.f, q = 0.f;
    for (int j = 0; j < 64; j++) { s += bnp[j * 2 * Ch + d]; q += bnp[j * 2 * Ch + Ch + d]; }
    float mean = s / bncnt;
    float var = fmaxf(q / bncnt - mean * mean, 0.f);
    float sc = bng[d] * rsqrtf(var + BN_EPS);
    sbn[d] = sc;
    sbn[Ch + d] = bnb[d] - mean * sc;
  }
  int mloc = t / TD;
  int dbase = t % TD;
  int DV = D / TD;  // 1 or 2
  __syncthreads();
  for (int s = 0; s < Gseq; s++) {
    int grp0 = (bid * Gseq + s) * Gpar;
    if (grp0 >= BM) break;
    int nf = Gpar * 16 * Cpad;
    for (int i = t; i < nf; i += 256) {
      int c = i % Cpad;
      int rk = i / Cpad;
      int k = rk & 15;
      int g = rk >> 4;
      int grp = grp0 + g;
      float val = 0.f;
      if (grp < BM && c < Ctot) {
        int b = grp / M;
        int nb = nidx[(size_t)grp * 16 + k];
        if (c < 3) {
          val = p[((size_t)b * N + nb) * 3 + c] - newp[(size_t)grp * 3 + c];
        } else {
          int cc = c - 3;
          float sc = sbn[cc], sh = sbn[Ch + cc];
          const float* hs = (sc >= 0.f) ? h : hmin;
          val = fmaxf(hs[((size_t)b * N + nb) * Ch + cc] * sc + sh, 0.f);
        }
      }
      sfeat[i] = val;
    }
    __syncthreads();
    int grp = grp0 + mloc;
    bool act = grp < BM;
    const float* fr = sfeat + mloc * 16 * Cpad;
    for (int dv = 0; dv < DV; ++dv) {
      int d = dbase + (dv << 8);
      float acc[16];
#pragma unroll
      for (int k = 0; k < 16; k++) acc[k] = 0.f;
      for (int c = 0; c < Cpad; c += 4) {
        float w0 = (c < Ctot) ? W[(size_t)c * D + d] : 0.f;
        float w1 = (c + 1 < Ctot) ? W[(size_t)(c + 1) * D + d] : 0.f;
        float w2 = (c + 2 < Ctot) ? W[(size_t)(c + 2) * D + d] : 0.f;
        float w3 = (c + 3 < Ctot) ? W[(size_t)(c + 3) * D + d] : 0.f;
#pragma unroll
        for (int k = 0; k < 16; k++) {
          const float4 f = *reinterpret_cast<const float4*>(fr + k * Cpad + c);
          acc[k] += f.x * w0 + f.y * w1 + f.z * w2 + f.w * w3;
        }
      }
      if (act) {
        float ssum = 0.f, ssq = 0.f, amax = -INFINITY, amin = INFINITY;
#pragma unroll
        for (int k = 0; k < 16; k++) {
          float a = acc[k];
          ssum += a; ssq += a * a;
          amax = fmaxf(amax, a); amin = fminf(amin, a);
        }
        ymax[(size_t)grp * D + d] = amax;
        ymin[(size_t)grp * D + d] = amin;
        atomicAdd(&sstat[d], ssum);
        atomicAdd(&sstat[D + d], ssq);
      }
    }
    __syncthreads();
  }
  for (int i = t; i < 2 * D; i += 256)
    atomicAdd(&partial[(bid & 63) * 2 * D + i], sstat[i]);
}

// ---------------- fused: fps1 (blocks 0-15) || mlp1 (blocks 16+) ----------------
__global__ void __launch_bounds__(256) fused_fps1_mlp1_kernel(
    const float* __restrict__ x, float* __restrict__ newp,
    const float* __restrict__ W1, float* __restrict__ h1, int rows) {
  __shared__ float spts[4096 * 3];
  __shared__ float snew[1024 * 3];
  __shared__ unsigned long long slots[8];
  const int t = threadIdx.x;
  if (blockIdx.x < 16) {
    fps_body<16, 4>(x + (size_t)blockIdx.x * 4096 * 3, newp + (size_t)blockIdx.x * 1024 * 3,
                    spts, snew, slots, t);
  } else {
    int tid = (blockIdx.x - 16) * 256 + t;
    int row = tid >> 5;
    int d = tid & 31;
    if (row < rows) {
      float x0 = x[row * 3 + 0], x1 = x[row * 3 + 1], x2 = x[row * 3 + 2];
      h1[row * 32 + d] = x0 * W1[d] + x1 * W1[32 + d] + x2 * W1[64 + d];
    }
  }
}

// ---------------- fused: knn1 || stats1 (thin: no fps LDS -> full occupancy) ----------------
__global__ void __launch_bounds__(256) fused_knn_stats_kernel(
    const float* __restrict__ kp, const float* __restrict__ knewp,
    int kN, int kM, int kBM, int* __restrict__ knidx, int nKnn,
    const float* __restrict__ sv, int sn, int sD, float* __restrict__ spartial, int nStats) {
  __shared__ float ssm[64];
  const int t = threadIdx.x;
  const int bid = blockIdx.x;
  if (bid < nKnn) {
    int gwid = (bid * 256 + t) >> 6;
    knn_body(kp, knewp, kN, kM, kBM, knidx, gwid, t & 63);
  } else {
    stats_body(sv, sn, sD, spartial, ssm, bid - nKnn, nStats, t);
  }
}

// ---------------- fused 3-way: gemm || fps || knn (any range may be empty) ----------------
template <int P, int NW>
__global__ void __launch_bounds__(256) fused_gfk_kernel(
    // gemm (+ inline input-BN)
    const float* __restrict__ p, const float* __restrict__ h,
    const float* __restrict__ hmin, const float* __restrict__ newp,
    const int* __restrict__ nidx, const float* __restrict__ W,
    const float* __restrict__ bnp, const float* __restrict__ bng,
    const float* __restrict__ bnb, float bncnt,
    float* __restrict__ ymax, float* __restrict__ ymin,
    float* __restrict__ partial, int N, int M, int BM, int Ch, int Cpad, int D,
    int Gseq, int nGemm,
    // fps
    const float* __restrict__ fp, float* __restrict__ fnewp, int nFps,
    // knn
    const float* __restrict__ kp, const float* __restrict__ knewp,
    int kN, int kM, int kBM, int* __restrict__ knidx) {
  constexpr int FBS = NW * 64;
  constexpr int FN = P * FBS;
  constexpr int FM = FN / 4;
  __shared__ float spts[FN * 3];
  __shared__ float snew[NW > 1 ? FM * 3 : 1];
  __shared__ unsigned long long slots[NW > 1 ? 2 * NW : 2];
  extern __shared__ float sm[];
  const int t = threadIdx.x;
  const int bid = blockIdx.x;
  if (bid < nGemm) {
    gemm_body(sm, p, h, hmin, newp, nidx, W, bnp, bng, bnb, bncnt,
              ymax, ymin, partial, N, M, BM, Ch, Cpad, D, Gseq, bid, t);
  } else if (bid < nGemm + nFps) {
    int fb = bid - nGemm;
    if (NW > 1 || t < 64) {
      fps_body<P, NW>(fp + (size_t)fb * FN * 3, fnewp + (size_t)fb * FM * 3,
                      spts, snew, slots, t);
    }
  } else {
    int gwid = ((bid - nGemm - nFps) * 256 + t) >> 6;
    knn_body(kp, knewp, kN, kM, kBM, knidx, gwid, t & 63);
  }
}

// ---------------- standalone gemm (stage 4) ----------------
__global__ void __launch_bounds__(256) gemm_kernel(
    const float* __restrict__ p, const float* __restrict__ h,
    const float* __restrict__ hmin, const float* __restrict__ newp,
    const int* __restrict__ nidx, const float* __restrict__ W,
    const float* __restrict__ bnp, const float* __restrict__ bng,
    const float* __restrict__ bnb, float bncnt,
    float* __restrict__ ymax, float* __restrict__ ymin,
    float* __restrict__ partial, int N, int M, int BM, int Ch, int Cpad, int D, int Gseq) {
  extern __shared__ float sm[];
  gemm_body(sm, p, h, hmin, newp, nidx, W, bnp, bng, bnb, bncnt,
            ymax, ymin, partial, N, M, BM, Ch, Cpad, D, Gseq, blockIdx.x, threadIdx.x);
}

// ---------------- classifier head with inline stage-4 BN ----------------
__global__ void __launch_bounds__(512) classifier_kernel(
    const float* __restrict__ h4, const float* __restrict__ h4min,
    const float* __restrict__ bnp, const float* __restrict__ bng,
    const float* __restrict__ bnb, float bncnt,
    const float* __restrict__ Wc1, const float* __restrict__ bc1,
    const float* __restrict__ gc1, const float* __restrict__ hc1,
    const float* __restrict__ Wc2, const float* __restrict__ bc2,
    const float* __restrict__ gc2, const float* __restrict__ hc2,
    const float* __restrict__ Wc3, const float* __restrict__ bc3,
    float* __restrict__ out) {
  __shared__ float z[16 * 512];
  __shared__ float z1[16 * 256];
  __shared__ float z2[16 * 128];
  __shared__ float sc[256], sh[256];
  __shared__ float s5[1024];
  int t = threadIdx.x;
  for (int d = t; d < 512; d += 512) {
    float s = 0.f, q = 0.f;
    for (int j = 0; j < 64; j++) { s += bnp[j * 1024 + d]; q += bnp[j * 1024 + 512 + d]; }
    float mean = s / bncnt;
    float var = fmaxf(q / bncnt - mean * mean, 0.f);
    float scv = bng[d] * rsqrtf(var + BN_EPS);
    s5[d] = scv;
    s5[512 + d] = bnb[d] - mean * scv;
  }
  __syncthreads();
  for (int i = t; i < 16 * 512; i += 512) {
    int b = i >> 9, c = i & 511;
    float scv = s5[c], shv = s5[512 + c];
    const float* src = (scv >= 0.f) ? h4 : h4min;
    float s = 0.f;
    for (int k = 0; k < 16; k++)
      s += fmaxf(src[((size_t)b * 16 + k) * 512 + c] * scv + shv, 0.f);
    z[i] = s * (1.f / 16.f);
  }
  __syncthreads();
  for (int i = t; i < 16 * 256; i += 512) {
    int b = i >> 8, d = i & 255;
    float a = bc1[d];
    for (int c = 0; c < 512; c++) a += z[(b << 9) + c] * Wc1[c * 256 + d];
    z1[i] = a;
  }
  __syncthreads();
  if (t < 256) {
    float s = 0.f, q = 0.f;
    for (int b = 0; b < 16; b++) { float a = z1[(b << 8) + t]; s += a; q += a * a; }
    float mean = s * (1.f / 16.f);
    float var = fmaxf(q * (1.f / 16.f) - mean * mean, 0.f);
    float scl = gc1[t] * rsqrtf(var + BN_EPS);
    sc[t] = scl; sh[t] = hc1[t] - mean * scl;
  }
  __syncthreads();
  for (int i = t; i < 16 * 256; i += 512) {
    int d = i & 255;
    z1[i] = fmaxf(z1[i] * sc[d] + sh[d], 0.f);
  }
  __syncthreads();
  for (int i = t; i < 16 * 128; i += 512) {
    int b = i >> 7, d = i & 127;
    float a = bc2[d];
    for (int c = 0; c < 256; c++) a += z1[(b << 8) + c] * Wc2[c * 128 + d];
    z2[i] = a;
  }
  __syncthreads();
  if (t < 128) {
    float s = 0.f, q = 0.f;
    for (int b = 0; b < 16; b++) { float a = z2[(b << 7) + t]; s += a; q += a * a; }
    float mean = s * (1.f / 16.f);
    float var = fmaxf(q * (1.f / 16.f) - mean * mean, 0.f);
    float scl = gc2[t] * rsqrtf(var + BN_EPS);
    sc[t] = scl; sh[t] = hc2[t] - mean * scl;
  }
  __syncthreads();
  for (int i = t; i < 16 * 128; i += 512) {
    int d = i & 127;
    z2[i] = fmaxf(z2[i] * sc[d] + sh[d], 0.f);
  }
  __syncthreads();
  for (int i = t; i < 640; i += 512) {
    int b = i / 40, d = i % 40;
    float a = bc3[d];
    for (int c = 0; c < 128; c++) a += z2[(b << 7) + c] * Wc3[c * 40 + d];
    out[i] = a;
  }
}

extern "C" void kernel_launch(void* const* d_in, const int* in_sizes, int n_in,
                              void* d_out, int out_size, void* d_ws, size_t ws_size,
                              hipStream_t stream) {
  (void)in_sizes; (void)n_in; (void)out_size; (void)ws_size;
  const float* x   = (const float*)d_in[0];
  const float* W1  = (const float*)d_in[1];
  const float* g1  = (const float*)d_in[2];
  const float* b1  = (const float*)d_in[3];
  const float* W2  = (const float*)d_in[4];
  const float* g2  = (const float*)d_in[5];
  const float* b2  = (const float*)d_in[6];
  const float* W3  = (const float*)d_in[7];
  const float* g3  = (const float*)d_in[8];
  const float* b3  = (const float*)d_in[9];
  const float* W4  = (const float*)d_in[10];
  const float* g4  = (const float*)d_in[11];
  const float* b4  = (const float*)d_in[12];
  const float* W5  = (const float*)d_in[13];
  const float* g5  = (const float*)d_in[14];
  const float* b5  = (const float*)d_in[15];
  const float* Wc1 = (const float*)d_in[16];
  const float* bc1 = (const float*)d_in[17];
  const float* gc1 = (const float*)d_in[18];
  const float* hc1 = (const float*)d_in[19];
  const float* Wc2 = (const float*)d_in[20];
  const float* bc2 = (const float*)d_in[21];
  const float* gc2 = (const float*)d_in[22];
  const float* hc2 = (const float*)d_in[23];
  const float* Wc3 = (const float*)d_in[24];
  const float* bc3 = (const float*)d_in[25];
  float* out = (float*)d_out;

  float* ws = (float*)d_ws;
  float* HA    = ws;                   // 2,097,152 (h1 raw; s2 ymax; s4 ymax)
  float* HB    = HA + 2097152;         // 1,048,576 (s1 ymax; s3 ymax)
  float* YMINA = HB + 1048576;         // 1,048,576 (s1, s3 ymin)
  float* YMINB = YMINA + 1048576;      // 524,288 (s2, s4 ymin)
  float* NP1   = YMINB + 524288;       // 49,152
  float* NP2   = NP1 + 49152;          // 12,288
  float* NP3   = NP2 + 12288;          // 3,072
  float* NP4   = NP3 + 3072;           // 768
  int*   NIDX1 = (int*)(NP4 + 768);    // 262,144 ints
  int*   NIDX2 = NIDX1 + 262144;       // 65,536 ints
  int*   NIDX3 = NIDX2 + 65536;        // 16,384 ints
  int*   NIDX4 = NIDX3 + 16384;        // 4,096 ints
  float* PART  = (float*)(NIDX4 + 4096);  // 5 * 65,536

  hipMemsetAsync(PART, 0, 5 * 65536 * sizeof(float), stream);

  // A: fps1 (x -> NP1) || mlp1 (x,W1 -> HA raw)
  fused_fps1_mlp1_kernel<<<16 + 8192, 256, 0, stream>>>(x, NP1, W1, HA, 65536);

  // B': knn1 (x,NP1 -> NIDX1) || stats1 (HA -> PART) — thin, full occupancy
  fused_knn_stats_kernel<<<4096 + 256, 256, 0, stream>>>(
      x, NP1, 4096, 1024, 16384, NIDX1, 4096,
      HA, 65536 * 32, 32, PART, 256);

  // C': gemm1 (bn1 inline) || fps2 (NP1->NP2) — fps2's ~120 µs chain hides
  // under gemm1 (previously fps2 was serialized BEFORE gemm1 in B).
  fused_gfk_kernel<4, 4><<<512 + 16, 256,
                           (4 * 16 * 36 + 2 * 64 + 2 * 32) * sizeof(float), stream>>>(
      x, HA, HA, NP1, NIDX1, W2, PART, g1, b1, 65536.f,
      HB, YMINA, PART + 65536, 4096, 1024, 16384, 32, 36, 64, 8, 512,
      NP1, NP2, 16,
      nullptr, nullptr, 1, 1, 0, nullptr);

  // D': fps3 (NP2->NP3) || knn2 (NP1,NP2 -> NIDX2)
  fused_gfk_kernel<4, 1><<<16 + 1024, 256, 0, stream>>>(
      nullptr, nullptr, nullptr, nullptr, nullptr, nullptr, nullptr, nullptr,
      nullptr, 1.f,
      nullptr, nullptr, nullptr, 1, 1, 0, 1, 4, 1, 1, 0,
      NP2, NP3, 16,
      NP1, NP2, 1024, 256, 4096, NIDX2);

  // E': gemm2 (bn2 inline) || fps4 (NP3->NP4) || knn3 (NP2,NP3 -> NIDX3)
  fused_gfk_kernel<1, 1><<<512 + 16 + 256, 256,
                           (2 * 16 * 68 + 2 * 128 + 2 * 64) * sizeof(float), stream>>>(
      NP1, HB, YMINA, NP2, NIDX2, W3, PART + 65536, g2, b2, (float)(16384 * 16),
      HA, YMINB, PART + 2 * 65536, 1024, 256, 4096, 64, 68, 128, 4, 512,
      NP3, NP4, 16,
      NP2, NP3, 256, 64, 1024, NIDX3);

  // F': gemm3 (bn3 inline) || knn4 (NP3,NP4 -> NIDX4)
  fused_gfk_kernel<1, 1><<<512 + 0 + 64, 256,
                           (16 * 132 + 2 * 256 + 2 * 128) * sizeof(float), stream>>>(
      NP2, HA, YMINB, NP3, NIDX3, W4, PART + 2 * 65536, g3, b3, (float)(4096 * 16),
      HB, YMINA, PART + 3 * 65536, 256, 64, 1024, 128, 132, 256, 2, 512,
      nullptr, nullptr, 0,
      NP3, NP4, 64, 16, 256, NIDX4);

  // gemm4 (bn4 inline)
  gemm_kernel<<<256, 256, (16 * 260 + 2 * 512 + 2 * 256) * sizeof(float), stream>>>(
      NP3, HB, YMINA, NP4, NIDX4, W5, PART + 3 * 65536, g4, b4, (float)(1024 * 16),
      HA, YMINB, PART + 4 * 65536, 64, 16, 256, 256, 260, 512, 1);

  // classifier (bn5 inline)
  classifier_kernel<<<1, 512, 0, stream>>>(
      HA, YMINB, PART + 4 * 65536, g5, b5, (float)(256 * 16),
      Wc1, bc1, gc1, hc1, Wc2, bc2, gc2, hc2, Wc3, bc3, out);
}

// Round 15
// 1325.146 us; speedup vs baseline: 1.0350x; 1.0350x over previous
//
#include <hip/hip_runtime.h>
#include <math.h>
#include <float.h>

#define BN_EPS 1e-5f

// Exact (non-contracted) squared distance, matching numpy's mul-then-add
// left-to-right association. Critical: FPS/KNN *selections* must match ref.
__device__ __forceinline__ float sqdist_exact(float dx, float dy, float dz) {
  return __fadd_rn(__fadd_rn(__fmul_rn(dx, dx), __fmul_rn(dy, dy)), __fmul_rn(dz, dz));
}

// ---------------- FPS v6: u64-key DPP reduce (proven best) ----------------
// Key = (float_bits(dist) << 32) | ~index  (dist>=0 => IEEE order == uint
// order; max key == max dist, first-index tie-break, matches jnp.argmax).
// Session lessons (rounds 2-14): <16,4> (1 wave/SIMD) is optimal for fps1;
// coord-carry through the DPP chain spills (v7/v8/v10); issue-count reduction
// is useless (v5/v11: latency-chain-bound). ~600 µs is fps1's floor.
// Scheduling: a long fps latency chain must NOT be co-resident with a long
// throughput kernel (round 14: fps2 under gemm1 stretched ~1.6x, regression);
// hide only short fps instances (fps3/fps4) under gemms.
#define DPP_STEP(CTRL)                                                                   \
  {                                                                                      \
    unsigned int nhi = (unsigned int)__builtin_amdgcn_update_dpp((int)khi, (int)khi,     \
                                                                 CTRL, 0xf, 0xf, false); \
    unsigned int nlo = (unsigned int)__builtin_amdgcn_update_dpp((int)klo, (int)klo,     \
                                                                 CTRL, 0xf, 0xf, false); \
    unsigned long long nk = (((unsigned long long)nhi) << 32) | nlo;                     \
    if (nk > wk) { wk = nk; khi = nhi; klo = nlo; }                                      \
  }

// fps body shared by fused kernels. Caller guarantees:
// - threads t in [0, NW*64) call this (NW==1 body has NO barriers);
// - for NW>1 all blockDim threads enter (barriers are block-local).
template <int P, int NW>
__device__ __forceinline__ void fps_body(const float* __restrict__ pb,
                                         float* __restrict__ newp_b,
                                         float* spts, float* snew,
                                         unsigned long long* slots, int t) {
  constexpr int BS = NW * 64;
  constexpr int N = P * BS;
  constexpr int M = N / 4;
  const int wv = t >> 6;
  const int lane = t & 63;
  float px[P], py[P], pz[P], md[P];
#pragma unroll
  for (int j = 0; j < P; j++) {
    int i = j * BS + t;
    float x = pb[3 * i], y = pb[3 * i + 1], z = pb[3 * i + 2];
    px[j] = x; py[j] = y; pz[j] = z; md[j] = INFINITY;
    spts[3 * i] = x; spts[3 * i + 1] = y; spts[3 * i + 2] = z;
  }
  float lx = pb[0], ly = pb[1], lz = pb[2];
  if (t == 0) {
    if constexpr (NW > 1) {
      snew[0] = lx; snew[1] = ly; snew[2] = lz;
    } else {
      newp_b[0] = lx; newp_b[1] = ly; newp_b[2] = lz;
    }
  }

  for (int r = 1; r < M; r++) {
    float bv; int bi;
    {
      float d0 = sqdist_exact(px[0] - lx, py[0] - ly, pz[0] - lz);
      float m0 = fminf(md[0], d0);
      md[0] = m0;
      bv = m0; bi = t;
    }
#pragma unroll
    for (int j = 1; j < P; j++) {
      float d = sqdist_exact(px[j] - lx, py[j] - ly, pz[j] - lz);
      float m = fminf(md[j], d);
      md[j] = m;
      if (m > bv) { bv = m; bi = j * BS + t; }  // strict >: first-index ties
    }
    unsigned int khi = __float_as_uint(bv);
    unsigned int klo = ~(unsigned int)bi;
    unsigned long long wk = (((unsigned long long)khi) << 32) | klo;
    DPP_STEP(0x111);  // row_shr:1
    DPP_STEP(0x112);  // row_shr:2
    DPP_STEP(0x114);  // row_shr:4
    DPP_STEP(0x118);  // row_shr:8
    DPP_STEP(0x142);  // row_bcast:15
    DPP_STEP(0x143);  // row_bcast:31
    unsigned int gidx;
    if constexpr (NW == 1) {
      unsigned int wlo = (unsigned int)__builtin_amdgcn_readlane((int)wk, 63);
      gidx = ~wlo;
    } else {
      unsigned long long* base = slots + (r & 1) * NW;
      if (lane == 63) base[wv] = wk;
      __syncthreads();
      unsigned long long fk = base[0];
#pragma unroll
      for (int w = 1; w < NW; w++) {
        unsigned long long k2 = base[w];
        if (k2 > fk) fk = k2;
      }
      gidx = ~(unsigned int)fk;
    }
    lx = spts[3 * gidx];
    ly = spts[3 * gidx + 1];
    lz = spts[3 * gidx + 2];
    if (t == 0) {
      if constexpr (NW > 1) {
        snew[3 * r] = lx; snew[3 * r + 1] = ly; snew[3 * r + 2] = lz;
      } else {
        newp_b[3 * r] = lx; newp_b[3 * r + 1] = ly; newp_b[3 * r + 2] = lz;
      }
    }
  }
  if constexpr (NW > 1) {
    __syncthreads();
    for (int i = t; i < M * 3; i += BS) newp_b[i] = snew[i];
  }
}

// knn body (no barriers).
__device__ __forceinline__ void knn_body(const float* __restrict__ p,
                                         const float* __restrict__ newp,
                                         int N, int M, int BM,
                                         int* __restrict__ nidx,
                                         int gwid, int lane) {
  if (gwid >= BM) return;
  int b = gwid / M;
  const float* pb = p + (size_t)b * N * 3;
  float qx = newp[(size_t)gwid * 3], qy = newp[(size_t)gwid * 3 + 1], qz = newp[(size_t)gwid * 3 + 2];
  float bd[16];
  int bi[16];
#pragma unroll
  for (int s = 0; s < 16; s++) { bd[s] = INFINITY; bi[s] = 0x7FFFFFFF; }
  for (int c = lane; c < N; c += 64) {
    float d = sqdist_exact(pb[3 * c] - qx, pb[3 * c + 1] - qy, pb[3 * c + 2] - qz);
    if (d < bd[15]) {
      bd[15] = d; bi[15] = c;
#pragma unroll
      for (int s = 15; s >= 1; --s) {
        bool sw = bd[s] < bd[s - 1];
        if (sw) {
          float tf = bd[s]; bd[s] = bd[s - 1]; bd[s - 1] = tf;
          int ti = bi[s]; bi[s] = bi[s - 1]; bi[s - 1] = ti;
        }
      }
    }
  }
  int out = 0;
  for (int r = 0; r < 16; r++) {
    float v = bd[0]; int ii = bi[0];
    float mv = v; int mi = ii;
#pragma unroll
    for (int m = 1; m < 64; m <<= 1) {
      float v2 = __shfl_xor(mv, m);
      int i2 = __shfl_xor(mi, m);
      if (v2 < mv || (v2 == mv && i2 < mi)) { mv = v2; mi = i2; }
    }
    if (mi == ii) {
#pragma unroll
      for (int s = 0; s < 15; s++) { bd[s] = bd[s + 1]; bi[s] = bi[s + 1]; }
      bd[15] = INFINITY; bi[15] = 0x7FFFFFFF;
    }
    if (lane == r) out = mi;
  }
  if (lane < 16) nidx[(size_t)gwid * 16 + lane] = out;
}

// stats body: per-channel sum/sumsq. Same tid/stride mapping as the original
// standalone stats_kernel (nb=256 virtual blocks) -> bit-identical per-thread
// partial sums; only atomic order differs (tolerated jitter).
__device__ __forceinline__ void stats_body(const float* __restrict__ v, int n, int D,
                                           float* __restrict__ partial, float* sm,
                                           int bid, int nb, int t) {
  int tid = bid * 256 + t;
  int stride = 256 * nb;
  float s = 0.f, q = 0.f;
  for (int i = tid; i < n; i += stride) { float a = v[i]; s += a; q += a * a; }
  int c = tid % D;
  for (int i = t; i < 2 * D; i += 256) sm[i] = 0.f;
  __syncthreads();
  atomicAdd(&sm[c], s);
  atomicAdd(&sm[D + c], q);
  __syncthreads();
  for (int i = t; i < 2 * D; i += 256)
    atomicAdd(&partial[(bid & 63) * 2 * D + i], sm[i]);
}

// gemm body with INLINE input-BN: computes scale/shift from the input stage's
// PART stats (same 64-slot j-order reduction as the old finalize/bn kernels ->
// bit-identical sc/sh), then applies fmax(raw*sc+sh, 0) per gathered element
// with a per-channel POINTER SELECT (sc>=0 ? ymax : ymin) -> single load.
// Removes the standalone bn kernel from the inter-stage critical path.
__device__ __forceinline__ void gemm_body(
    float* sm, const float* __restrict__ p, const float* __restrict__ h,
    const float* __restrict__ hmin, const float* __restrict__ newp,
    const int* __restrict__ nidx, const float* __restrict__ W,
    const float* __restrict__ bnp, const float* __restrict__ bng,
    const float* __restrict__ bnb, float bncnt,
    float* __restrict__ ymax, float* __restrict__ ymin,
    float* __restrict__ partial, int N, int M, int BM, int Ch, int Cpad, int D,
    int Gseq, int bid, int t) {
  int Ctot = Ch + 3;
  int TD = D < 256 ? D : 256;
  int Gpar = 256 / TD;
  float* sfeat = sm;                      // Gpar*16*Cpad
  float* sstat = sm + Gpar * 16 * Cpad;   // 2*D
  float* sbn   = sstat + 2 * D;           // 2*Ch
  for (int i = t; i < 2 * D; i += 256) sstat[i] = 0.f;
  for (int d = t; d < Ch; d += 256) {
    float s = 0.f, q = 0.f;
    for (int j = 0; j < 64; j++) { s += bnp[j * 2 * Ch + d]; q += bnp[j * 2 * Ch + Ch + d]; }
    float mean = s / bncnt;
    float var = fmaxf(q / bncnt - mean * mean, 0.f);
    float sc = bng[d] * rsqrtf(var + BN_EPS);
    sbn[d] = sc;
    sbn[Ch + d] = bnb[d] - mean * sc;
  }
  int mloc = t / TD;
  int dbase = t % TD;
  int DV = D / TD;  // 1 or 2
  __syncthreads();
  for (int s = 0; s < Gseq; s++) {
    int grp0 = (bid * Gseq + s) * Gpar;
    if (grp0 >= BM) break;
    int nf = Gpar * 16 * Cpad;
    for (int i = t; i < nf; i += 256) {
      int c = i % Cpad;
      int rk = i / Cpad;
      int k = rk & 15;
      int g = rk >> 4;
      int grp = grp0 + g;
      float val = 0.f;
      if (grp < BM && c < Ctot) {
        int b = grp / M;
        int nb = nidx[(size_t)grp * 16 + k];
        if (c < 3) {
          val = p[((size_t)b * N + nb) * 3 + c] - newp[(size_t)grp * 3 + c];
        } else {
          int cc = c - 3;
          float sc = sbn[cc], sh = sbn[Ch + cc];
          const float* hs = (sc >= 0.f) ? h : hmin;
          val = fmaxf(hs[((size_t)b * N + nb) * Ch + cc] * sc + sh, 0.f);
        }
      }
      sfeat[i] = val;
    }
    __syncthreads();
    int grp = grp0 + mloc;
    bool act = grp < BM;
    const float* fr = sfeat + mloc * 16 * Cpad;
    for (int dv = 0; dv < DV; ++dv) {
      int d = dbase + (dv << 8);
      float acc[16];
#pragma unroll
      for (int k = 0; k < 16; k++) acc[k] = 0.f;
      for (int c = 0; c < Cpad; c += 4) {
        float w0 = (c < Ctot) ? W[(size_t)c * D + d] : 0.f;
        float w1 = (c + 1 < Ctot) ? W[(size_t)(c + 1) * D + d] : 0.f;
        float w2 = (c + 2 < Ctot) ? W[(size_t)(c + 2) * D + d] : 0.f;
        float w3 = (c + 3 < Ctot) ? W[(size_t)(c + 3) * D + d] : 0.f;
#pragma unroll
        for (int k = 0; k < 16; k++) {
          const float4 f = *reinterpret_cast<const float4*>(fr + k * Cpad + c);
          acc[k] += f.x * w0 + f.y * w1 + f.z * w2 + f.w * w3;
        }
      }
      if (act) {
        float ssum = 0.f, ssq = 0.f, amax = -INFINITY, amin = INFINITY;
#pragma unroll
        for (int k = 0; k < 16; k++) {
          float a = acc[k];
          ssum += a; ssq += a * a;
          amax = fmaxf(amax, a); amin = fminf(amin, a);
        }
        ymax[(size_t)grp * D + d] = amax;
        ymin[(size_t)grp * D + d] = amin;
        atomicAdd(&sstat[d], ssum);
        atomicAdd(&sstat[D + d], ssq);
      }
    }
    __syncthreads();
  }
  for (int i = t; i < 2 * D; i += 256)
    atomicAdd(&partial[(bid & 63) * 2 * D + i], sstat[i]);
}

// ---------------- fused: fps1 (blocks 0-15) || mlp1 (blocks 16+) ----------------
__global__ void __launch_bounds__(256) fused_fps1_mlp1_kernel(
    const float* __restrict__ x, float* __restrict__ newp,
    const float* __restrict__ W1, float* __restrict__ h1, int rows) {
  __shared__ float spts[4096 * 3];
  __shared__ float snew[1024 * 3];
  __shared__ unsigned long long slots[8];
  const int t = threadIdx.x;
  if (blockIdx.x < 16) {
    fps_body<16, 4>(x + (size_t)blockIdx.x * 4096 * 3, newp + (size_t)blockIdx.x * 1024 * 3,
                    spts, snew, slots, t);
  } else {
    int tid = (blockIdx.x - 16) * 256 + t;
    int row = tid >> 5;
    int d = tid & 31;
    if (row < rows) {
      float x0 = x[row * 3 + 0], x1 = x[row * 3 + 1], x2 = x[row * 3 + 2];
      h1[row * 32 + d] = x0 * W1[d] + x1 * W1[32 + d] + x2 * W1[64 + d];
    }
  }
}

// ---------------- fused: fps2 || knn1 || stats1 ----------------
__global__ void __launch_bounds__(256) fused_fks_kernel(
    const float* __restrict__ fp, float* __restrict__ fnewp,
    const float* __restrict__ kp, const float* __restrict__ knewp,
    int kN, int kM, int kBM, int* __restrict__ knidx, int nKnn,
    const float* __restrict__ sv, int sn, int sD, float* __restrict__ spartial, int nStats) {
  __shared__ float spts[1024 * 3];
  __shared__ float snew[256 * 3];
  __shared__ unsigned long long slots[8];
  __shared__ float ssm[64];
  const int t = threadIdx.x;
  const int bid = blockIdx.x;
  if (bid < 16) {
    fps_body<4, 4>(fp + (size_t)bid * 1024 * 3, fnewp + (size_t)bid * 256 * 3,
                   spts, snew, slots, t);
  } else if (bid < 16 + nKnn) {
    int gwid = ((bid - 16) * 256 + t) >> 6;
    knn_body(kp, knewp, kN, kM, kBM, knidx, gwid, t & 63);
  } else {
    stats_body(sv, sn, sD, spartial, ssm, bid - 16 - nKnn, nStats, t);
  }
}

// ---------------- fused 3-way: gemm(k) || fps(k+2) || knn(k+1) ----------------
template <int P, int NW>
__global__ void __launch_bounds__(256) fused_gfk_kernel(
    // gemm (+ inline input-BN)
    const float* __restrict__ p, const float* __restrict__ h,
    const float* __restrict__ hmin, const float* __restrict__ newp,
    const int* __restrict__ nidx, const float* __restrict__ W,
    const float* __restrict__ bnp, const float* __restrict__ bng,
    const float* __restrict__ bnb, float bncnt,
    float* __restrict__ ymax, float* __restrict__ ymin,
    float* __restrict__ partial, int N, int M, int BM, int Ch, int Cpad, int D,
    int Gseq, int nGemm,
    // fps
    const float* __restrict__ fp, float* __restrict__ fnewp, int nFps,
    // knn
    const float* __restrict__ kp, const float* __restrict__ knewp,
    int kN, int kM, int kBM, int* __restrict__ knidx) {
  constexpr int FBS = NW * 64;
  constexpr int FN = P * FBS;
  constexpr int FM = FN / 4;
  __shared__ float spts[FN * 3];
  __shared__ float snew[NW > 1 ? FM * 3 : 1];
  __shared__ unsigned long long slots[NW > 1 ? 2 * NW : 2];
  extern __shared__ float sm[];
  const int t = threadIdx.x;
  const int bid = blockIdx.x;
  if (bid < nGemm) {
    gemm_body(sm, p, h, hmin, newp, nidx, W, bnp, bng, bnb, bncnt,
              ymax, ymin, partial, N, M, BM, Ch, Cpad, D, Gseq, bid, t);
  } else if (bid < nGemm + nFps) {
    int fb = bid - nGemm;
    if (NW > 1 || t < 64) {
      fps_body<P, NW>(fp + (size_t)fb * FN * 3, fnewp + (size_t)fb * FM * 3,
                      spts, snew, slots, t);
    }
  } else {
    int gwid = ((bid - nGemm - nFps) * 256 + t) >> 6;
    knn_body(kp, knewp, kN, kM, kBM, knidx, gwid, t & 63);
  }
}

// ---------------- standalone gemm (stage 4) ----------------
__global__ void __launch_bounds__(256) gemm_kernel(
    const float* __restrict__ p, const float* __restrict__ h,
    const float* __restrict__ hmin, const float* __restrict__ newp,
    const int* __restrict__ nidx, const float* __restrict__ W,
    const float* __restrict__ bnp, const float* __restrict__ bng,
    const float* __restrict__ bnb, float bncnt,
    float* __restrict__ ymax, float* __restrict__ ymin,
    float* __restrict__ partial, int N, int M, int BM, int Ch, int Cpad, int D, int Gseq) {
  extern __shared__ float sm[];
  gemm_body(sm, p, h, hmin, newp, nidx, W, bnp, bng, bnb, bncnt,
            ymax, ymin, partial, N, M, BM, Ch, Cpad, D, Gseq, blockIdx.x, threadIdx.x);
}

// ---------------- classifier head with inline stage-4 BN ----------------
__global__ void __launch_bounds__(512) classifier_kernel(
    const float* __restrict__ h4, const float* __restrict__ h4min,
    const float* __restrict__ bnp, const float* __restrict__ bng,
    const float* __restrict__ bnb, float bncnt,
    const float* __restrict__ Wc1, const float* __restrict__ bc1,
    const float* __restrict__ gc1, const float* __restrict__ hc1,
    const float* __restrict__ Wc2, const float* __restrict__ bc2,
    const float* __restrict__ gc2, const float* __restrict__ hc2,
    const float* __restrict__ Wc3, const float* __restrict__ bc3,
    float* __restrict__ out) {
  __shared__ float z[16 * 512];
  __shared__ float z1[16 * 256];
  __shared__ float z2[16 * 128];
  __shared__ float sc[256], sh[256];
  __shared__ float s5[1024];
  int t = threadIdx.x;
  for (int d = t; d < 512; d += 512) {
    float s = 0.f, q = 0.f;
    for (int j = 0; j < 64; j++) { s += bnp[j * 1024 + d]; q += bnp[j * 1024 + 512 + d]; }
    float mean = s / bncnt;
    float var = fmaxf(q / bncnt - mean * mean, 0.f);
    float scv = bng[d] * rsqrtf(var + BN_EPS);
    s5[d] = scv;
    s5[512 + d] = bnb[d] - mean * scv;
  }
  __syncthreads();
  for (int i = t; i < 16 * 512; i += 512) {
    int b = i >> 9, c = i & 511;
    float scv = s5[c], shv = s5[512 + c];
    const float* src = (scv >= 0.f) ? h4 : h4min;
    float s = 0.f;
    for (int k = 0; k < 16; k++)
      s += fmaxf(src[((size_t)b * 16 + k) * 512 + c] * scv + shv, 0.f);
    z[i] = s * (1.f / 16.f);
  }
  __syncthreads();
  for (int i = t; i < 16 * 256; i += 512) {
    int b = i >> 8, d = i & 255;
    float a = bc1[d];
    for (int c = 0; c < 512; c++) a += z[(b << 9) + c] * Wc1[c * 256 + d];
    z1[i] = a;
  }
  __syncthreads();
  if (t < 256) {
    float s = 0.f, q = 0.f;
    for (int b = 0; b < 16; b++) { float a = z1[(b << 8) + t]; s += a; q += a * a; }
    float mean = s * (1.f / 16.f);
    float var = fmaxf(q * (1.f / 16.f) - mean * mean, 0.f);
    float scl = gc1[t] * rsqrtf(var + BN_EPS);
    sc[t] = scl; sh[t] = hc1[t] - mean * scl;
  }
  __syncthreads();
  for (int i = t; i < 16 * 256; i += 512) {
    int d = i & 255;
    z1[i] = fmaxf(z1[i] * sc[d] + sh[d], 0.f);
  }
  __syncthreads();
  for (int i = t; i < 16 * 128; i += 512) {
    int b = i >> 7, d = i & 127;
    float a = bc2[d];
    for (int c = 0; c < 256; c++) a += z1[(b << 8) + c] * Wc2[c * 128 + d];
    z2[i] = a;
  }
  __syncthreads();
  if (t < 128) {
    float s = 0.f, q = 0.f;
    for (int b = 0; b < 16; b++) { float a = z2[(b << 7) + t]; s += a; q += a * a; }
    float mean = s * (1.f / 16.f);
    float var = fmaxf(q * (1.f / 16.f) - mean * mean, 0.f);
    float scl = gc2[t] * rsqrtf(var + BN_EPS);
    sc[t] = scl; sh[t] = hc2[t] - mean * scl;
  }
  __syncthreads();
  for (int i = t; i < 16 * 128; i += 512) {
    int d = i & 127;
    z2[i] = fmaxf(z2[i] * sc[d] + sh[d], 0.f);
  }
  __syncthreads();
  for (int i = t; i < 640; i += 512) {
    int b = i / 40, d = i % 40;
    float a = bc3[d];
    for (int c = 0; c < 128; c++) a += z2[(b << 7) + c] * Wc3[c * 40 + d];
    out[i] = a;
  }
}

extern "C" void kernel_launch(void* const* d_in, const int* in_sizes, int n_in,
                              void* d_out, int out_size, void* d_ws, size_t ws_size,
                              hipStream_t stream) {
  (void)in_sizes; (void)n_in; (void)out_size; (void)ws_size;
  const float* x   = (const float*)d_in[0];
  const float* W1  = (const float*)d_in[1];
  const float* g1  = (const float*)d_in[2];
  const float* b1  = (const float*)d_in[3];
  const float* W2  = (const float*)d_in[4];
  const float* g2  = (const float*)d_in[5];
  const float* b2  = (const float*)d_in[6];
  const float* W3  = (const float*)d_in[7];
  const float* g3  = (const float*)d_in[8];
  const float* b3  = (const float*)d_in[9];
  const float* W4  = (const float*)d_in[10];
  const float* g4  = (const float*)d_in[11];
  const float* b4  = (const float*)d_in[12];
  const float* W5  = (const float*)d_in[13];
  const float* g5  = (const float*)d_in[14];
  const float* b5  = (const float*)d_in[15];
  const float* Wc1 = (const float*)d_in[16];
  const float* bc1 = (const float*)d_in[17];
  const float* gc1 = (const float*)d_in[18];
  const float* hc1 = (const float*)d_in[19];
  const float* Wc2 = (const float*)d_in[20];
  const float* bc2 = (const float*)d_in[21];
  const float* gc2 = (const float*)d_in[22];
  const float* hc2 = (const float*)d_in[23];
  const float* Wc3 = (const float*)d_in[24];
  const float* bc3 = (const float*)d_in[25];
  float* out = (float*)d_out;

  float* ws = (float*)d_ws;
  float* HA    = ws;                   // 2,097,152 (h1 raw; s2 ymax; s4 ymax)
  float* HB    = HA + 2097152;         // 1,048,576 (s1 ymax; s3 ymax)
  float* YMINA = HB + 1048576;         // 1,048,576 (s1, s3 ymin)
  float* YMINB = YMINA + 1048576;      // 524,288 (s2, s4 ymin)
  float* NP1   = YMINB + 524288;       // 49,152
  float* NP2   = NP1 + 49152;          // 12,288
  float* NP3   = NP2 + 12288;          // 3,072
  float* NP4   = NP3 + 3072;           // 768
  int*   NIDX1 = (int*)(NP4 + 768);    // 262,144 ints
  int*   NIDX2 = NIDX1 + 262144;       // 65,536 ints
  int*   NIDX3 = NIDX2 + 65536;        // 16,384 ints
  int*   NIDX4 = NIDX3 + 16384;        // 4,096 ints
  float* PART  = (float*)(NIDX4 + 4096);  // 5 * 65,536

  hipMemsetAsync(PART, 0, 5 * 65536 * sizeof(float), stream);

  // A: fps1 (x -> NP1) || mlp1 (x,W1 -> HA raw)
  fused_fps1_mlp1_kernel<<<16 + 8192, 256, 0, stream>>>(x, NP1, W1, HA, 65536);

  // B: fps2 (NP1->NP2) || knn1 (x,NP1 -> NIDX1) || stats1 (HA -> PART)
  fused_fks_kernel<<<16 + 4096 + 256, 256, 0, stream>>>(
      NP1, NP2, x, NP1, 4096, 1024, 16384, NIDX1, 4096,
      HA, 65536 * 32, 32, PART, 256);

  // F2: gemm1 (bn1 inline: PART,g1,b1; h=hmin=HA) || fps3 || knn2
  fused_gfk_kernel<4, 1><<<512 + 16 + 1024, 256,
                           (4 * 16 * 36 + 2 * 64 + 2 * 32) * sizeof(float), stream>>>(
      x, HA, HA, NP1, NIDX1, W2, PART, g1, b1, 65536.f,
      HB, YMINA, PART + 65536, 4096, 1024, 16384, 32, 36, 64, 8, 512,
      NP2, NP3, 16,
      NP1, NP2, 1024, 256, 4096, NIDX2);

  // F3: gemm2 (bn2 inline: PART1,g2,b2; h=HB, hmin=YMINA) || fps4 || knn3
  fused_gfk_kernel<1, 1><<<512 + 16 + 256, 256,
                           (2 * 16 * 68 + 2 * 128 + 2 * 64) * sizeof(float), stream>>>(
      NP1, HB, YMINA, NP2, NIDX2, W3, PART + 65536, g2, b2, (float)(16384 * 16),
      HA, YMINB, PART + 2 * 65536, 1024, 256, 4096, 64, 68, 128, 4, 512,
      NP3, NP4, 16,
      NP2, NP3, 256, 64, 1024, NIDX3);

  // F4: gemm3 (bn3 inline: PART2,g3,b3; h=HA, hmin=YMINB) || knn4
  fused_gfk_kernel<1, 1><<<512 + 0 + 64, 256,
                           (16 * 132 + 2 * 256 + 2 * 128) * sizeof(float), stream>>>(
      NP2, HA, YMINB, NP3, NIDX3, W4, PART + 2 * 65536, g3, b3, (float)(4096 * 16),
      HB, YMINA, PART + 3 * 65536, 256, 64, 1024, 128, 132, 256, 2, 512,
      nullptr, nullptr, 0,
      NP3, NP4, 64, 16, 256, NIDX4);

  // gemm4 (bn4 inline: PART3,g4,b4; h=HB, hmin=YMINA)
  gemm_kernel<<<256, 256, (16 * 260 + 2 * 512 + 2 * 256) * sizeof(float), stream>>>(
      NP3, HB, YMINA, NP4, NIDX4, W5, PART + 3 * 65536, g4, b4, (float)(1024 * 16),
      HA, YMINB, PART + 4 * 65536, 64, 16, 256, 256, 260, 512, 1);

  // classifier (bn5 inline: PART4,g5,b5; h4=HA, h4min=YMINB)
  classifier_kernel<<<1, 512, 0, stream>>>(
      HA, YMINB, PART + 4 * 65536, g5, b5, (float)(256 * 16),
      Wc1, bc1, gc1, hc1, Wc2, bc2, gc2, hc2, Wc3, bc3, out);
}